// Round 5
// baseline (286.168 us; speedup 1.0000x reference)
//
#include <hip/hip_runtime.h>

#define BB 512
#define DD 128
#define HD 64

// ---- workspace layout (float offsets) ----
#define OFF_E1 0                     // 3 * 512 * 128  (normalized emb1, packed (d, d+64))
#define OFF_E2 (3*BB*DD)             // 3 * 512 * 128
#define OFF_C1 (2*3*BB*DD)           // 2 * 512 * 128  (cert1 layers 1,2 packed)
#define OFF_C2 (OFF_C1 + 2*BB*DD)    // 2 * 512 * 128
#define OFF_AB (OFF_C2 + 2*BB*DD)    // 2 layers * (A[128], B[128]); A=-log2e*alpha, B=-log2e*beta
#define OFF_LNK (OFF_AB + 512)       // 2 links * (idx[3][128] int, w[3][128] float) = 2*768
#define WS_FLOATS (OFF_LNK + 1536)   // ~2.51 MB

__device__ __forceinline__ float wave_sum64(float v) {
  #pragma unroll
  for (int off = 1; off < 64; off <<= 1) v += __shfl_xor(v, off, 64);
  return v;
}

// DPP lane-shift add: pure VALU pipe (no LDS). Sum of all 64 lanes lands in lane 63.
template <int CTRL>
__device__ __forceinline__ float dpp_mov(float x) {
  int i = __builtin_bit_cast(int, x);
  int r = __builtin_amdgcn_update_dpp(0, i, CTRL, 0xF, 0xF, false);
  return __builtin_bit_cast(float, r);
}
__device__ __forceinline__ float dpp_wave_sum_lane63(float v) {
  v += dpp_mov<0x111>(v);  // row_shr:1
  v += dpp_mov<0x112>(v);  // row_shr:2
  v += dpp_mov<0x114>(v);  // row_shr:4
  v += dpp_mov<0x118>(v);  // row_shr:8  -> lane15 of each row16 has row sum
  v += dpp_mov<0x142>(v);  // row_bcast:15 -> lane31 = S(0:31), lane63 = S(32:63)
  v += dpp_mov<0x143>(v);  // row_bcast:31 -> lane63 = S(0:63)
  return v;
}

// ---- merged prep ----
// blocks 0..1279: normalize/pack rows (5120 row-tasks, one wave each)
// blocks 1280..1343: link top-3, one wave per (link, column) task (256 tasks)
struct PackArgs { const float* src[10]; };

__global__ __launch_bounds__(256) void prep_kernel(PackArgs a,
                                                   const float* __restrict__ lnk0,
                                                   const float* __restrict__ lnk1,
                                                   const float* __restrict__ a1,
                                                   const float* __restrict__ b1,
                                                   const float* __restrict__ a2,
                                                   const float* __restrict__ b2,
                                                   float* __restrict__ ws) {
  const int tid  = threadIdx.x;
  const int lane = tid & 63;
  if (blockIdx.x < 1280) {
    const int gw   = blockIdx.x * 4 + (tid >> 6);
    const int arr  = gw >> 9;                       // 0..9
    const int row  = gw & 511;
    const float* s = a.src[arr];
    float lo = s[row * DD + lane];
    float hi = s[row * DD + lane + 64];
    float scale = 1.0f;
    if (arr < 6) {  // embeddings: L2 normalize
      float ss = wave_sum64(lo * lo + hi * hi);
      scale = 1.0f / fmaxf(sqrtf(ss), 1e-12f);
    }
    float* dst;
    if (arr < 3)      dst = ws + OFF_E1 + arr * (BB * DD);
    else if (arr < 6) dst = ws + OFF_E2 + (arr - 3) * (BB * DD);
    else if (arr < 8) dst = ws + OFF_C1 + (arr - 6) * (BB * DD);
    else              dst = ws + OFF_C2 + (arr - 8) * (BB * DD);
    ((float2*)dst)[row * HD + lane] = make_float2(lo * scale, hi * scale);
  } else {
    // one wave per (l, e) column; lane d holds L[d][e] and L[d+64][e]
    const int task = (blockIdx.x - 1280) * 4 + (tid >> 6);   // 0..255
    const int l = task >> 7, e = task & 127;
    const float* L = l ? lnk1 : lnk0;
    float v0 = L[lane * DD + e];
    float v1 = L[(lane + 64) * DD + e];
    float bv[3]; int bd[3];
    #pragma unroll
    for (int k = 0; k < 3; ++k) {
      float lv; int ld;
      if (v0 >= v1) { lv = v0; ld = lane; } else { lv = v1; ld = lane + 64; }
      #pragma unroll
      for (int off = 1; off < 64; off <<= 1) {
        float ov = __shfl_xor(lv, off, 64);
        int   od = __shfl_xor(ld, off, 64);
        if (ov > lv || (ov == lv && od < ld)) { lv = ov; ld = od; }
      }
      bv[k] = lv; bd[k] = ld;             // same in all lanes
      if (ld == lane)      v0 = -1e30f;   // remove winner
      if (ld == lane + 64) v1 = -1e30f;
    }
    if (lane == 0) {
      float inv = 1.0f / (bv[0] + bv[1] + bv[2] + 1e-8f);
      int*   li = (int*)(ws + OFF_LNK + l * 768);
      float* lw =        ws + OFF_LNK + l * 768 + 384;
      // indices pre-transformed for interleaved LDS h-layout:
      // dim d lives at LDS word ((d&63)<<1) | (d>>6)
      li[e]       = ((bd[0] & 63) << 1) | (bd[0] >> 6);
      li[128 + e] = ((bd[1] & 63) << 1) | (bd[1] >> 6);
      li[256 + e] = ((bd[2] & 63) << 1) | (bd[2] >> 6);
      lw[e] = bv[0] * inv; lw[128 + e] = bv[1] * inv; lw[256 + e] = bv[2] * inv;
      const float NL2E = -1.4426950408889634f;
      const float* al = l ? a2 : a1;
      const float* bl = l ? b2 : b1;
      ws[OFF_AB + l * 256 + e]       = NL2E * al[e];
      ws[OFF_AB + l * 256 + 128 + e] = NL2E * bl[e];
    }
  }
}

// ---- main: one wave per (i-tile of 4) x (j-chunk of 8); lane owns dims (lane, lane+64).
// R4 post-mortem: grid 1024 (4 blocks/CU, 2.5 waves/SIMD) was latency-bound
// (VALU 56%, LDS ~60%, neither saturated). j-chunk 16->8 doubles grid to 2048
// blocks = 8 blocks/CU; VGPR=64 permits 8 waves/SIMD, __launch_bounds__(256,8)
// pins the allocator there.
__global__ __launch_bounds__(256, 8) void main_kernel(const float* __restrict__ ws,
                                                      float* __restrict__ out) {
  __shared__ float hbuf[4][DD];
  const int tid  = threadIdx.x;
  const int lane = tid & 63;
  const int w    = tid >> 6;
  float* hb = hbuf[w];
  float2* hb2 = (float2*)hb;             // hb2[l] = (dim l, dim l+64)
  const int gw = blockIdx.x * 4 + w;     // 8192 waves
  const int i0 = (gw >> 6) * 4;          // 128 i-tiles of 4
  const int j0 = (gw & 63) * 8;          // 64 j-chunks of 8

  const int*   li0 = (const int*)(ws + OFF_LNK);
  const float* lw0 = ws + OFF_LNK + 384;
  const int*   li1 = (const int*)(ws + OFF_LNK + 768);
  const float* lw1 = ws + OFF_LNK + 768 + 384;
  int I1[3][2], I2[3][2]; float W1[3][2], W2[3][2];
  #pragma unroll
  for (int k = 0; k < 3; ++k) {
    I1[k][0] = li0[k * 128 + lane]; I1[k][1] = li0[k * 128 + lane + 64];
    W1[k][0] = lw0[k * 128 + lane]; W1[k][1] = lw0[k * 128 + lane + 64];
    I2[k][0] = li1[k * 128 + lane]; I2[k][1] = li1[k * 128 + lane + 64];
    W2[k][0] = lw1[k * 128 + lane]; W2[k][1] = lw1[k * 128 + lane + 64];
  }
  const float A1lo = ws[OFF_AB + lane],       A1hi = ws[OFF_AB + lane + 64];
  const float B1lo = ws[OFF_AB + 128 + lane], B1hi = ws[OFF_AB + 128 + lane + 64];
  const float A2lo = ws[OFF_AB + 256 + lane], A2hi = ws[OFF_AB + 256 + lane + 64];
  const float B2lo = ws[OFF_AB + 384 + lane], B2hi = ws[OFF_AB + 384 + lane + 64];

  const float2* E1p = (const float2*)(ws + OFF_E1);
  const float2* E2p = (const float2*)(ws + OFF_E2);
  const float2* C1p = (const float2*)(ws + OFF_C1);
  const float2* C2p = (const float2*)(ws + OFF_C2);

  // i-tile setup: gather u0 at layer-1 indices once per ii (amortized over 8 j's)
  float U[4][3][2];       // -2*w1_k*u0[d_k]
  float SU[4][2];         // Sum_k w1_k*u0[d_k]^2
  float2 u1[4], u2[4], c11[4], c12[4];
  #pragma unroll
  for (int ii = 0; ii < 4; ++ii) {
    const int i = i0 + ii;
    float2 u0 = E1p[(0 * BB + i) * HD + lane];
    hb2[lane] = u0;                               // same-wave DS: in-order, no barrier
    SU[ii][0] = 0.0f; SU[ii][1] = 0.0f;
    #pragma unroll
    for (int k = 0; k < 3; ++k) {
      float alo = hb[I1[k][0]], ahi = hb[I1[k][1]];
      float tlo = W1[k][0] * alo, thi = W1[k][1] * ahi;
      SU[ii][0] = fmaf(tlo, alo, SU[ii][0]);
      SU[ii][1] = fmaf(thi, ahi, SU[ii][1]);
      U[ii][k][0] = -2.0f * tlo;
      U[ii][k][1] = -2.0f * thi;
    }
    u1[ii]  = E1p[(1 * BB + i) * HD + lane];
    u2[ii]  = E1p[(2 * BB + i) * HD + lane];
    c11[ii] = C1p[(0 * BB + i) * HD + lane];
    c12[ii] = C1p[(1 * BB + i) * HD + lane];
  }

  #pragma unroll 1
  for (int jj = 0; jj < 8; ++jj) {
    const int j = j0 + jj;
    float2 v0 = E2p[(0 * BB + j) * HD + lane];
    hb2[lane] = v0;
    float V[3][2], SVlo = 0.0f, SVhi = 0.0f;
    #pragma unroll
    for (int k = 0; k < 3; ++k) {
      float clo = hb[I1[k][0]], chi = hb[I1[k][1]];
      V[k][0] = clo; V[k][1] = chi;
      SVlo = fmaf(W1[k][0] * clo, clo, SVlo);
      SVhi = fmaf(W1[k][1] * chi, chi, SVhi);
    }
    const float2 v1  = E2p[(1 * BB + j) * HD + lane];
    const float2 v2  = E2p[(2 * BB + j) * HD + lane];
    const float2 g21 = C2p[(0 * BB + j) * HD + lane];
    const float2 g22 = C2p[(1 * BB + j) * HD + lane];
    #pragma unroll
    for (int ii = 0; ii < 4; ++ii) {
      // layer 1: g0 from factored gathers (registers only)
      float glo = fmaf(U[ii][0][0], V[0][0],
                  fmaf(U[ii][1][0], V[1][0],
                  fmaf(U[ii][2][0], V[2][0], SU[ii][0] + SVlo)));
      float ghi = fmaf(U[ii][0][1], V[0][1],
                  fmaf(U[ii][1][1], V[1][1],
                  fmaf(U[ii][2][1], V[2][1], SU[ii][1] + SVhi)));
      float dx = u1[ii].x - v1.x, dy = u1[ii].y - v1.y;
      float nlo = dx * dx, nhi = dy * dy;
      float tlo = __builtin_amdgcn_exp2f(fmaf(c11[ii].x * g21.x, A1lo, B1lo));
      float thi = __builtin_amdgcn_exp2f(fmaf(c11[ii].y * g21.y, A1hi, B1hi));
      float Plo = __builtin_amdgcn_rcpf(1.0f + tlo);   // P = sigmoid(alpha*eta+beta)
      float Phi = __builtin_amdgcn_rcpf(1.0f + thi);
      float hlo = fmaf(Plo, nlo - glo, glo);           // (1-P)*g + P*n
      float hhi = fmaf(Phi, nhi - ghi, ghi);
      // layer 2: per-pair LDS gather (P is pair-dependent); one b64 spill
      hb2[lane] = make_float2(hlo, hhi);
      glo = hb[I2[0][0]] * W2[0][0] + hb[I2[1][0]] * W2[1][0] + hb[I2[2][0]] * W2[2][0];
      ghi = hb[I2[0][1]] * W2[0][1] + hb[I2[1][1]] * W2[1][1] + hb[I2[2][1]] * W2[2][1];
      dx = u2[ii].x - v2.x; dy = u2[ii].y - v2.y;
      nlo = dx * dx; nhi = dy * dy;
      tlo = __builtin_amdgcn_exp2f(fmaf(c12[ii].x * g22.x, A2lo, B2lo));
      thi = __builtin_amdgcn_exp2f(fmaf(c12[ii].y * g22.y, A2hi, B2hi));
      Plo = __builtin_amdgcn_rcpf(1.0f + tlo);
      Phi = __builtin_amdgcn_rcpf(1.0f + thi);
      hlo = fmaf(Plo, nlo - glo, glo);
      hhi = fmaf(Phi, nhi - ghi, ghi);
      // reduce over 128 dims: DPP (VALU pipe), sum lands in lane 63
      float s = dpp_wave_sum_lane63(hlo + hhi);
      if (lane == 63) out[(i0 + ii) * BB + j] = s;
    }
  }
}

extern "C" void kernel_launch(void* const* d_in, const int* in_sizes, int n_in,
                              void* d_out, int out_size, void* d_ws, size_t ws_size,
                              hipStream_t stream) {
  (void)in_sizes; (void)n_in; (void)out_size; (void)ws_size;
  // dict order: [0]emb1_0 [1]emb2_0 [2]cert1_0 [3]cert2_0 [4]alpha_0 [5]beta_0
  //             [6..11] layer1, [12..17] layer2, [18]link_0 [19]link_1
  float* ws = (float*)d_ws;
  PackArgs pa;
  pa.src[0] = (const float*)d_in[0];  pa.src[1] = (const float*)d_in[6];  pa.src[2] = (const float*)d_in[12];
  pa.src[3] = (const float*)d_in[1];  pa.src[4] = (const float*)d_in[7];  pa.src[5] = (const float*)d_in[13];
  pa.src[6] = (const float*)d_in[8];  pa.src[7] = (const float*)d_in[14];
  pa.src[8] = (const float*)d_in[9];  pa.src[9] = (const float*)d_in[15];
  hipLaunchKernelGGL(prep_kernel, dim3(1344), dim3(256), 0, stream, pa,
                     (const float*)d_in[18], (const float*)d_in[19],
                     (const float*)d_in[10], (const float*)d_in[11],
                     (const float*)d_in[16], (const float*)d_in[17], ws);
  hipLaunchKernelGGL(main_kernel, dim3(2048), dim3(256), 0, stream,
                     (const float*)ws, (float*)d_out);
}

// Round 6
// 137.757 us; speedup vs baseline: 2.0773x; 2.0773x over previous
//
#include <hip/hip_runtime.h>

#define BB 512
#define DD 128
#define HD 64

// ---- workspace layout (float offsets) ----
#define OFF_E1 0                     // 3 * 512 * 128  (normalized emb1, packed (d, d+64))
#define OFF_E2 (3*BB*DD)             // 3 * 512 * 128
#define OFF_C1 (2*3*BB*DD)           // 2 * 512 * 128  (cert1 layers 1,2 packed)
#define OFF_C2 (OFF_C1 + 2*BB*DD)    // 2 * 512 * 128
#define OFF_AB (OFF_C2 + 2*BB*DD)    // 2 layers * (A[128], B[128]); A=-log2e*alpha, B=-log2e*beta
#define OFF_LNK (OFF_AB + 512)       // 2 links * (idx[3][128] int, w[3][128] float) = 2*768
#define WS_FLOATS (OFF_LNK + 1536)   // ~2.51 MB

__device__ __forceinline__ float wave_sum64(float v) {
  #pragma unroll
  for (int off = 1; off < 64; off <<= 1) v += __shfl_xor(v, off, 64);
  return v;
}

// DPP lane-shift add: pure VALU pipe (no LDS). Sum of all 64 lanes lands in lane 63.
template <int CTRL>
__device__ __forceinline__ float dpp_mov(float x) {
  int i = __builtin_bit_cast(int, x);
  int r = __builtin_amdgcn_update_dpp(0, i, CTRL, 0xF, 0xF, false);
  return __builtin_bit_cast(float, r);
}
__device__ __forceinline__ float dpp_wave_sum_lane63(float v) {
  v += dpp_mov<0x111>(v);  // row_shr:1
  v += dpp_mov<0x112>(v);  // row_shr:2
  v += dpp_mov<0x114>(v);  // row_shr:4
  v += dpp_mov<0x118>(v);  // row_shr:8  -> lane15 of each row16 has row sum
  v += dpp_mov<0x142>(v);  // row_bcast:15 -> lane31 = S(0:31), lane63 = S(32:63)
  v += dpp_mov<0x143>(v);  // row_bcast:31 -> lane63 = S(0:63)
  return v;
}

// ---- merged prep ----
// blocks 0..1279: normalize/pack rows (5120 row-tasks, one wave each)
// blocks 1280..1343: link top-3, one wave per (link, column) task (256 tasks)
struct PackArgs { const float* src[10]; };

__global__ __launch_bounds__(256) void prep_kernel(PackArgs a,
                                                   const float* __restrict__ lnk0,
                                                   const float* __restrict__ lnk1,
                                                   const float* __restrict__ a1,
                                                   const float* __restrict__ b1,
                                                   const float* __restrict__ a2,
                                                   const float* __restrict__ b2,
                                                   float* __restrict__ ws) {
  const int tid  = threadIdx.x;
  const int lane = tid & 63;
  if (blockIdx.x < 1280) {
    const int gw   = blockIdx.x * 4 + (tid >> 6);
    const int arr  = gw >> 9;                       // 0..9
    const int row  = gw & 511;
    const float* s = a.src[arr];
    float lo = s[row * DD + lane];
    float hi = s[row * DD + lane + 64];
    float scale = 1.0f;
    if (arr < 6) {  // embeddings: L2 normalize
      float ss = wave_sum64(lo * lo + hi * hi);
      scale = 1.0f / fmaxf(sqrtf(ss), 1e-12f);
    }
    float* dst;
    if (arr < 3)      dst = ws + OFF_E1 + arr * (BB * DD);
    else if (arr < 6) dst = ws + OFF_E2 + (arr - 3) * (BB * DD);
    else if (arr < 8) dst = ws + OFF_C1 + (arr - 6) * (BB * DD);
    else              dst = ws + OFF_C2 + (arr - 8) * (BB * DD);
    ((float2*)dst)[row * HD + lane] = make_float2(lo * scale, hi * scale);
  } else {
    // one wave per (l, e) column; lane d holds L[d][e] and L[d+64][e]
    const int task = (blockIdx.x - 1280) * 4 + (tid >> 6);   // 0..255
    const int l = task >> 7, e = task & 127;
    const float* L = l ? lnk1 : lnk0;
    float v0 = L[lane * DD + e];
    float v1 = L[(lane + 64) * DD + e];
    float bv[3]; int bd[3];
    #pragma unroll
    for (int k = 0; k < 3; ++k) {
      float lv; int ld;
      if (v0 >= v1) { lv = v0; ld = lane; } else { lv = v1; ld = lane + 64; }
      #pragma unroll
      for (int off = 1; off < 64; off <<= 1) {
        float ov = __shfl_xor(lv, off, 64);
        int   od = __shfl_xor(ld, off, 64);
        if (ov > lv || (ov == lv && od < ld)) { lv = ov; ld = od; }
      }
      bv[k] = lv; bd[k] = ld;             // same in all lanes
      if (ld == lane)      v0 = -1e30f;   // remove winner
      if (ld == lane + 64) v1 = -1e30f;
    }
    if (lane == 0) {
      float inv = 1.0f / (bv[0] + bv[1] + bv[2] + 1e-8f);
      int*   li = (int*)(ws + OFF_LNK + l * 768);
      float* lw =        ws + OFF_LNK + l * 768 + 384;
      // indices pre-transformed for interleaved LDS h-layout:
      // dim d lives at LDS word ((d&63)<<1) | (d>>6)
      li[e]       = ((bd[0] & 63) << 1) | (bd[0] >> 6);
      li[128 + e] = ((bd[1] & 63) << 1) | (bd[1] >> 6);
      li[256 + e] = ((bd[2] & 63) << 1) | (bd[2] >> 6);
      lw[e] = bv[0] * inv; lw[128 + e] = bv[1] * inv; lw[256 + e] = bv[2] * inv;
      const float NL2E = -1.4426950408889634f;
      const float* al = l ? a2 : a1;
      const float* bl = l ? b2 : b1;
      ws[OFF_AB + l * 256 + e]       = NL2E * al[e];
      ws[OFF_AB + l * 256 + 128 + e] = NL2E * bl[e];
    }
  }
}

// ---- main: one wave per (i-tile of 4) x (j-chunk of 8); lane owns dims (lane, lane+64).
// R5 post-mortem: __launch_bounds__(256,8) forced VGPR=32 -> scratch spills
// (FETCH 565 MB, 196 us). KEEP (256,4): R4 allocated 64 VGPR under it, spill-free,
// and 64 VGPR still lets HW run 8 blocks/CU with the 2048-block grid.
__global__ __launch_bounds__(256, 4) void main_kernel(const float* __restrict__ ws,
                                                      float* __restrict__ out) {
  __shared__ float hbuf[4][DD];
  const int tid  = threadIdx.x;
  const int lane = tid & 63;
  const int w    = tid >> 6;
  float* hb = hbuf[w];
  float2* hb2 = (float2*)hb;             // hb2[l] = (dim l, dim l+64)
  const int gw = blockIdx.x * 4 + w;     // 8192 waves
  const int i0 = (gw >> 6) * 4;          // 128 i-tiles of 4
  const int j0 = (gw & 63) * 8;          // 64 j-chunks of 8

  const int*   li0 = (const int*)(ws + OFF_LNK);
  const float* lw0 = ws + OFF_LNK + 384;
  const int*   li1 = (const int*)(ws + OFF_LNK + 768);
  const float* lw1 = ws + OFF_LNK + 768 + 384;
  int I1[3][2], I2[3][2]; float W1[3][2], W2[3][2];
  #pragma unroll
  for (int k = 0; k < 3; ++k) {
    I1[k][0] = li0[k * 128 + lane]; I1[k][1] = li0[k * 128 + lane + 64];
    W1[k][0] = lw0[k * 128 + lane]; W1[k][1] = lw0[k * 128 + lane + 64];
    I2[k][0] = li1[k * 128 + lane]; I2[k][1] = li1[k * 128 + lane + 64];
    W2[k][0] = lw1[k * 128 + lane]; W2[k][1] = lw1[k * 128 + lane + 64];
  }
  const float A1lo = ws[OFF_AB + lane],       A1hi = ws[OFF_AB + lane + 64];
  const float B1lo = ws[OFF_AB + 128 + lane], B1hi = ws[OFF_AB + 128 + lane + 64];
  const float A2lo = ws[OFF_AB + 256 + lane], A2hi = ws[OFF_AB + 256 + lane + 64];
  const float B2lo = ws[OFF_AB + 384 + lane], B2hi = ws[OFF_AB + 384 + lane + 64];

  const float2* E1p = (const float2*)(ws + OFF_E1);
  const float2* E2p = (const float2*)(ws + OFF_E2);
  const float2* C1p = (const float2*)(ws + OFF_C1);
  const float2* C2p = (const float2*)(ws + OFF_C2);

  // i-tile setup: gather u0 at layer-1 indices once per ii (amortized over 8 j's)
  float U[4][3][2];       // -2*w1_k*u0[d_k]
  float SU[4][2];         // Sum_k w1_k*u0[d_k]^2
  float2 u1[4], u2[4], c11[4], c12[4];
  #pragma unroll
  for (int ii = 0; ii < 4; ++ii) {
    const int i = i0 + ii;
    float2 u0 = E1p[(0 * BB + i) * HD + lane];
    hb2[lane] = u0;                               // same-wave DS: in-order, no barrier
    SU[ii][0] = 0.0f; SU[ii][1] = 0.0f;
    #pragma unroll
    for (int k = 0; k < 3; ++k) {
      float alo = hb[I1[k][0]], ahi = hb[I1[k][1]];
      float tlo = W1[k][0] * alo, thi = W1[k][1] * ahi;
      SU[ii][0] = fmaf(tlo, alo, SU[ii][0]);
      SU[ii][1] = fmaf(thi, ahi, SU[ii][1]);
      U[ii][k][0] = -2.0f * tlo;
      U[ii][k][1] = -2.0f * thi;
    }
    u1[ii]  = E1p[(1 * BB + i) * HD + lane];
    u2[ii]  = E1p[(2 * BB + i) * HD + lane];
    c11[ii] = C1p[(0 * BB + i) * HD + lane];
    c12[ii] = C1p[(1 * BB + i) * HD + lane];
  }

  #pragma unroll 1
  for (int jj = 0; jj < 8; ++jj) {
    const int j = j0 + jj;
    float2 v0 = E2p[(0 * BB + j) * HD + lane];
    hb2[lane] = v0;
    float V[3][2], SVlo = 0.0f, SVhi = 0.0f;
    #pragma unroll
    for (int k = 0; k < 3; ++k) {
      float clo = hb[I1[k][0]], chi = hb[I1[k][1]];
      V[k][0] = clo; V[k][1] = chi;
      SVlo = fmaf(W1[k][0] * clo, clo, SVlo);
      SVhi = fmaf(W1[k][1] * chi, chi, SVhi);
    }
    const float2 v1  = E2p[(1 * BB + j) * HD + lane];
    const float2 v2  = E2p[(2 * BB + j) * HD + lane];
    const float2 g21 = C2p[(0 * BB + j) * HD + lane];
    const float2 g22 = C2p[(1 * BB + j) * HD + lane];
    #pragma unroll
    for (int ii = 0; ii < 4; ++ii) {
      // layer 1: g0 from factored gathers (registers only)
      float glo = fmaf(U[ii][0][0], V[0][0],
                  fmaf(U[ii][1][0], V[1][0],
                  fmaf(U[ii][2][0], V[2][0], SU[ii][0] + SVlo)));
      float ghi = fmaf(U[ii][0][1], V[0][1],
                  fmaf(U[ii][1][1], V[1][1],
                  fmaf(U[ii][2][1], V[2][1], SU[ii][1] + SVhi)));
      float dx = u1[ii].x - v1.x, dy = u1[ii].y - v1.y;
      float nlo = dx * dx, nhi = dy * dy;
      float tlo = __builtin_amdgcn_exp2f(fmaf(c11[ii].x * g21.x, A1lo, B1lo));
      float thi = __builtin_amdgcn_exp2f(fmaf(c11[ii].y * g21.y, A1hi, B1hi));
      float Plo = __builtin_amdgcn_rcpf(1.0f + tlo);   // P = sigmoid(alpha*eta+beta)
      float Phi = __builtin_amdgcn_rcpf(1.0f + thi);
      float hlo = fmaf(Plo, nlo - glo, glo);           // (1-P)*g + P*n
      float hhi = fmaf(Phi, nhi - ghi, ghi);
      // layer 2: per-pair LDS gather (P is pair-dependent); one b64 spill
      hb2[lane] = make_float2(hlo, hhi);
      glo = hb[I2[0][0]] * W2[0][0] + hb[I2[1][0]] * W2[1][0] + hb[I2[2][0]] * W2[2][0];
      ghi = hb[I2[0][1]] * W2[0][1] + hb[I2[1][1]] * W2[1][1] + hb[I2[2][1]] * W2[2][1];
      dx = u2[ii].x - v2.x; dy = u2[ii].y - v2.y;
      nlo = dx * dx; nhi = dy * dy;
      tlo = __builtin_amdgcn_exp2f(fmaf(c12[ii].x * g22.x, A2lo, B2lo));
      thi = __builtin_amdgcn_exp2f(fmaf(c12[ii].y * g22.y, A2hi, B2hi));
      Plo = __builtin_amdgcn_rcpf(1.0f + tlo);
      Phi = __builtin_amdgcn_rcpf(1.0f + thi);
      hlo = fmaf(Plo, nlo - glo, glo);
      hhi = fmaf(Phi, nhi - ghi, ghi);
      // reduce over 128 dims: DPP (VALU pipe), sum lands in lane 63
      float s = dpp_wave_sum_lane63(hlo + hhi);
      if (lane == 63) out[(i0 + ii) * BB + j] = s;
    }
  }
}

extern "C" void kernel_launch(void* const* d_in, const int* in_sizes, int n_in,
                              void* d_out, int out_size, void* d_ws, size_t ws_size,
                              hipStream_t stream) {
  (void)in_sizes; (void)n_in; (void)out_size; (void)ws_size;
  // dict order: [0]emb1_0 [1]emb2_0 [2]cert1_0 [3]cert2_0 [4]alpha_0 [5]beta_0
  //             [6..11] layer1, [12..17] layer2, [18]link_0 [19]link_1
  float* ws = (float*)d_ws;
  PackArgs pa;
  pa.src[0] = (const float*)d_in[0];  pa.src[1] = (const float*)d_in[6];  pa.src[2] = (const float*)d_in[12];
  pa.src[3] = (const float*)d_in[1];  pa.src[4] = (const float*)d_in[7];  pa.src[5] = (const float*)d_in[13];
  pa.src[6] = (const float*)d_in[8];  pa.src[7] = (const float*)d_in[14];
  pa.src[8] = (const float*)d_in[9];  pa.src[9] = (const float*)d_in[15];
  hipLaunchKernelGGL(prep_kernel, dim3(1344), dim3(256), 0, stream, pa,
                     (const float*)d_in[18], (const float*)d_in[19],
                     (const float*)d_in[10], (const float*)d_in[11],
                     (const float*)d_in[16], (const float*)d_in[17], ws);
  hipLaunchKernelGGL(main_kernel, dim3(2048), dim3(256), 0, stream,
                     (const float*)ws, (float*)d_out);
}

// Round 8
// 135.096 us; speedup vs baseline: 2.1183x; 1.0197x over previous
//
#include <hip/hip_runtime.h>

#define BB 512
#define DD 128
#define HD 64

typedef float v2f __attribute__((ext_vector_type(2)));
#define FMA2(a, b, c) __builtin_elementwise_fma((v2f)(a), (v2f)(b), (v2f)(c))

// ---- workspace layout (float offsets) ----
#define OFF_E1 0                     // 3 * 512 * 128  (normalized emb1, packed (d, d+64))
#define OFF_E2 (3*BB*DD)             // 3 * 512 * 128
#define OFF_C1 (2*3*BB*DD)           // 2 * 512 * 128  (cert1 layers 1,2 packed)
#define OFF_C2 (OFF_C1 + 2*BB*DD)    // 2 * 512 * 128
#define OFF_AB (OFF_C2 + 2*BB*DD)    // 2 layers * (A[128], B[128]); A=-log2e*alpha, B=-log2e*beta
#define OFF_LNK (OFF_AB + 512)       // 2 links * (idx[3][128] interleaved, w[3][128]) = 2*768
#define WS_FLOATS (OFF_LNK + 1536)   // ~2.51 MB

__device__ __forceinline__ float wave_sum64(float v) {
  #pragma unroll
  for (int off = 1; off < 64; off <<= 1) v += __shfl_xor(v, off, 64);
  return v;
}

// DPP lane-shift add: pure VALU pipe. Sum of all 64 lanes lands in lane 63.
template <int CTRL>
__device__ __forceinline__ float dpp_mov(float x) {
  int i = __builtin_bit_cast(int, x);
  int r = __builtin_amdgcn_update_dpp(0, i, CTRL, 0xF, 0xF, false);
  return __builtin_bit_cast(float, r);
}
__device__ __forceinline__ float dpp_wave_sum_lane63(float v) {
  v += dpp_mov<0x111>(v);  // row_shr:1
  v += dpp_mov<0x112>(v);  // row_shr:2
  v += dpp_mov<0x114>(v);  // row_shr:4
  v += dpp_mov<0x118>(v);  // row_shr:8
  v += dpp_mov<0x142>(v);  // row_bcast:15
  v += dpp_mov<0x143>(v);  // row_bcast:31
  return v;
}

// ---- merged prep (R6-verified verbatim) ----
// blocks 0..1279: normalize/pack rows (5120 row-tasks, one wave each)
// blocks 1280..1343: link top-3, one wave per (link, column) task (256 tasks)
struct PackArgs { const float* src[10]; };

__global__ __launch_bounds__(256) void prep_kernel(PackArgs a,
                                                   const float* __restrict__ lnk0,
                                                   const float* __restrict__ lnk1,
                                                   const float* __restrict__ a1,
                                                   const float* __restrict__ b1,
                                                   const float* __restrict__ a2,
                                                   const float* __restrict__ b2,
                                                   float* __restrict__ ws) {
  const int tid  = threadIdx.x;
  const int lane = tid & 63;
  if (blockIdx.x < 1280) {
    const int gw   = blockIdx.x * 4 + (tid >> 6);
    const int arr  = gw >> 9;                       // 0..9
    const int row  = gw & 511;
    const float* s = a.src[arr];
    float lo = s[row * DD + lane];
    float hi = s[row * DD + lane + 64];
    float scale = 1.0f;
    if (arr < 6) {  // embeddings: L2 normalize
      float ss = wave_sum64(lo * lo + hi * hi);
      scale = 1.0f / fmaxf(sqrtf(ss), 1e-12f);
    }
    float* dst;
    if (arr < 3)      dst = ws + OFF_E1 + arr * (BB * DD);
    else if (arr < 6) dst = ws + OFF_E2 + (arr - 3) * (BB * DD);
    else if (arr < 8) dst = ws + OFF_C1 + (arr - 6) * (BB * DD);
    else              dst = ws + OFF_C2 + (arr - 8) * (BB * DD);
    ((float2*)dst)[row * HD + lane] = make_float2(lo * scale, hi * scale);
  } else {
    // one wave per (l, e) column; lane d holds L[d][e] and L[d+64][e]
    const int task = (blockIdx.x - 1280) * 4 + (tid >> 6);   // 0..255
    const int l = task >> 7, e = task & 127;
    const float* L = l ? lnk1 : lnk0;
    float v0 = L[lane * DD + e];
    float v1 = L[(lane + 64) * DD + e];
    float bv[3]; int bd[3];
    #pragma unroll
    for (int k = 0; k < 3; ++k) {
      float lv; int ld;
      if (v0 >= v1) { lv = v0; ld = lane; } else { lv = v1; ld = lane + 64; }
      #pragma unroll
      for (int off = 1; off < 64; off <<= 1) {
        float ov = __shfl_xor(lv, off, 64);
        int   od = __shfl_xor(ld, off, 64);
        if (ov > lv || (ov == lv && od < ld)) { lv = ov; ld = od; }
      }
      bv[k] = lv; bd[k] = ld;             // same in all lanes
      if (ld == lane)      v0 = -1e30f;   // remove winner
      if (ld == lane + 64) v1 = -1e30f;
    }
    if (lane == 0) {
      float inv = 1.0f / (bv[0] + bv[1] + bv[2] + 1e-8f);
      int*   li = (int*)(ws + OFF_LNK + l * 768);
      float* lw =        ws + OFF_LNK + l * 768 + 384;
      // indices pre-transformed for interleaved LDS h-layout:
      // dim d lives at LDS word ((d&63)<<1) | (d>>6)
      li[e]       = ((bd[0] & 63) << 1) | (bd[0] >> 6);
      li[128 + e] = ((bd[1] & 63) << 1) | (bd[1] >> 6);
      li[256 + e] = ((bd[2] & 63) << 1) | (bd[2] >> 6);
      lw[e] = bv[0] * inv; lw[128 + e] = bv[1] * inv; lw[256 + e] = bv[2] * inv;
      const float NL2E = -1.4426950408889634f;
      const float* al = l ? a2 : a1;
      const float* bl = l ? b2 : b1;
      ws[OFF_AB + l * 256 + e]       = NL2E * al[e];
      ws[OFF_AB + l * 256 + 128 + e] = NL2E * bl[e];
    }
  }
}

// ---- main: R6-verified skeleton (float2 LDS stores, float LDS loads, same-wave
// DS ordering) with ONE change: arithmetic packed as v2f -> v_pk_{fma,mul,add}_f32.
// R7 post-mortem: v2f-typed LDS stores + bpermute both changed at once and broke
// correctness (absmax 0.375); suspected TBAA reorder of vector-store vs scalar-load.
// Here LDS access types are exactly R6's.
__global__ __launch_bounds__(256, 4) void main_kernel(const float* __restrict__ ws,
                                                      float* __restrict__ out) {
  __shared__ float hbuf[4][DD];
  const int tid  = threadIdx.x;
  const int lane = tid & 63;
  const int w    = tid >> 6;
  float*  hb  = hbuf[w];
  float2* hb2 = (float2*)hb;             // hb2[l] = (dim l, dim l+64)  [R6-verified]
  const int gw = blockIdx.x * 4 + w;     // 4096 waves
  const int i0 = (gw >> 5) * 4;          // 128 i-tiles of 4
  const int j0 = (gw & 31) * 16;         // 32 j-chunks of 16

  const int*   li0 = (const int*)(ws + OFF_LNK);
  const float* lw0 = ws + OFF_LNK + 384;
  const int*   li1 = (const int*)(ws + OFF_LNK + 768);
  const float* lw1 = ws + OFF_LNK + 768 + 384;
  int I1[3][2], I2[3][2]; v2f W1[3], W2[3];
  #pragma unroll
  for (int k = 0; k < 3; ++k) {
    I1[k][0] = li0[k * 128 + lane]; I1[k][1] = li0[k * 128 + lane + 64];
    W1[k].x  = lw0[k * 128 + lane]; W1[k].y  = lw0[k * 128 + lane + 64];
    I2[k][0] = li1[k * 128 + lane]; I2[k][1] = li1[k * 128 + lane + 64];
    W2[k].x  = lw1[k * 128 + lane]; W2[k].y  = lw1[k * 128 + lane + 64];
  }
  v2f Av1, Bv1, Av2, Bv2;
  Av1.x = ws[OFF_AB + lane];       Av1.y = ws[OFF_AB + lane + 64];
  Bv1.x = ws[OFF_AB + 128 + lane]; Bv1.y = ws[OFF_AB + 128 + lane + 64];
  Av2.x = ws[OFF_AB + 256 + lane]; Av2.y = ws[OFF_AB + 256 + lane + 64];
  Bv2.x = ws[OFF_AB + 384 + lane]; Bv2.y = ws[OFF_AB + 384 + lane + 64];

  const float2* E1p = (const float2*)(ws + OFF_E1);
  const float2* E2p = (const float2*)(ws + OFF_E2);
  const float2* C1p = (const float2*)(ws + OFF_C1);
  const float2* C2p = (const float2*)(ws + OFF_C2);
  #define LD2(p, idx) ({ float2 _t = (p)[idx]; v2f _v; _v.x = _t.x; _v.y = _t.y; _v; })

  // i-tile setup: gather u0 at layer-1 indices once per ii (amortized over 16 j's)
  v2f U[4][3];            // -2*w1_k*u0[d_k]
  v2f SU[4];              // Sum_k w1_k*u0[d_k]^2
  v2f u1[4], u2[4], c11[4], c12[4];
  #pragma unroll
  for (int ii = 0; ii < 4; ++ii) {
    const int i = i0 + ii;
    float2 u0 = E1p[(0 * BB + i) * HD + lane];
    hb2[lane] = u0;                               // same-wave DS: in-order, no barrier
    SU[ii] = (v2f)0.0f;
    #pragma unroll
    for (int k = 0; k < 3; ++k) {
      v2f a; a.x = hb[I1[k][0]]; a.y = hb[I1[k][1]];
      v2f t = W1[k] * a;
      SU[ii] = FMA2(t, a, SU[ii]);
      U[ii][k] = -2.0f * t;
    }
    u1[ii]  = LD2(E1p, (1 * BB + i) * HD + lane);
    u2[ii]  = LD2(E1p, (2 * BB + i) * HD + lane);
    c11[ii] = LD2(C1p, (0 * BB + i) * HD + lane);
    c12[ii] = LD2(C1p, (1 * BB + i) * HD + lane);
  }

  #pragma unroll 1
  for (int jj = 0; jj < 16; ++jj) {
    const int j = j0 + jj;
    float2 v0 = E2p[(0 * BB + j) * HD + lane];
    hb2[lane] = v0;
    v2f V[3], SV = (v2f)0.0f;
    #pragma unroll
    for (int k = 0; k < 3; ++k) {
      v2f c; c.x = hb[I1[k][0]]; c.y = hb[I1[k][1]];
      V[k] = c;
      SV = FMA2(W1[k] * c, c, SV);
    }
    const v2f v1  = LD2(E2p, (1 * BB + j) * HD + lane);
    const v2f v2  = LD2(E2p, (2 * BB + j) * HD + lane);
    const v2f g21 = LD2(C2p, (0 * BB + j) * HD + lane);
    const v2f g22 = LD2(C2p, (1 * BB + j) * HD + lane);
    #pragma unroll
    for (int ii = 0; ii < 4; ++ii) {
      // layer 1: g from factored gathers (registers only, pk-fma)
      v2f g1 = FMA2(U[ii][0], V[0], FMA2(U[ii][1], V[1], FMA2(U[ii][2], V[2], SU[ii] + SV)));
      v2f d1 = u1[ii] - v1;
      v2f n1 = d1 * d1;
      v2f x1 = FMA2(c11[ii] * g21, Av1, Bv1);
      v2f t1, P1;
      t1.x = __builtin_amdgcn_exp2f(x1.x); t1.y = __builtin_amdgcn_exp2f(x1.y);
      P1.x = __builtin_amdgcn_rcpf(1.0f + t1.x); P1.y = __builtin_amdgcn_rcpf(1.0f + t1.y);
      v2f h1 = FMA2(P1, n1 - g1, g1);           // (1-P)*g + P*n
      // layer 2: per-pair LDS gather (R6-verified float2-store/float-load pattern)
      hb2[lane] = make_float2(h1.x, h1.y);
      v2f g2;
      g2.x = hb[I2[0][0]] * W2[0].x + hb[I2[1][0]] * W2[1].x + hb[I2[2][0]] * W2[2].x;
      g2.y = hb[I2[0][1]] * W2[0].y + hb[I2[1][1]] * W2[1].y + hb[I2[2][1]] * W2[2].y;
      v2f d2 = u2[ii] - v2;
      v2f n2 = d2 * d2;
      v2f x2 = FMA2(c12[ii] * g22, Av2, Bv2);
      v2f t2, P2;
      t2.x = __builtin_amdgcn_exp2f(x2.x); t2.y = __builtin_amdgcn_exp2f(x2.y);
      P2.x = __builtin_amdgcn_rcpf(1.0f + t2.x); P2.y = __builtin_amdgcn_rcpf(1.0f + t2.y);
      v2f h2 = FMA2(P2, n2 - g2, g2);
      // reduce over 128 dims: DPP (VALU pipe), sum lands in lane 63
      float s = dpp_wave_sum_lane63(h2.x + h2.y);
      if (lane == 63) out[(i0 + ii) * BB + j] = s;
    }
  }
}

extern "C" void kernel_launch(void* const* d_in, const int* in_sizes, int n_in,
                              void* d_out, int out_size, void* d_ws, size_t ws_size,
                              hipStream_t stream) {
  (void)in_sizes; (void)n_in; (void)out_size; (void)ws_size;
  // dict order: [0]emb1_0 [1]emb2_0 [2]cert1_0 [3]cert2_0 [4]alpha_0 [5]beta_0
  //             [6..11] layer1, [12..17] layer2, [18]link_0 [19]link_1
  float* ws = (float*)d_ws;
  PackArgs pa;
  pa.src[0] = (const float*)d_in[0];  pa.src[1] = (const float*)d_in[6];  pa.src[2] = (const float*)d_in[12];
  pa.src[3] = (const float*)d_in[1];  pa.src[4] = (const float*)d_in[7];  pa.src[5] = (const float*)d_in[13];
  pa.src[6] = (const float*)d_in[8];  pa.src[7] = (const float*)d_in[14];
  pa.src[8] = (const float*)d_in[9];  pa.src[9] = (const float*)d_in[15];
  hipLaunchKernelGGL(prep_kernel, dim3(1344), dim3(256), 0, stream, pa,
                     (const float*)d_in[18], (const float*)d_in[19],
                     (const float*)d_in[10], (const float*)d_in[11],
                     (const float*)d_in[16], (const float*)d_in[17], ws);
  hipLaunchKernelGGL(main_kernel, dim3(1024), dim3(256), 0, stream,
                     (const float*)ws, (float*)d_out);
}